// Round 1
// baseline (1161.216 us; speedup 1.0000x reference)
//
#include <hip/hip_runtime.h>
#include <math.h>
#include <stdint.h>
#include <stddef.h>

#define BB 256
#define HHDIM 1024
#define DDIM 512
#define VDIM 50257
#define MMEM 100000

typedef __attribute__((ext_vector_type(8))) short bf8_t;       // 8 x bf16 (4 VGPR)
typedef __attribute__((ext_vector_type(4))) float f4_t;
typedef __attribute__((ext_vector_type(4))) unsigned short us4_t;

static __device__ __forceinline__ unsigned short f2bf(float x) {
    union { float f; uint32_t u; } a; a.f = x;
    uint32_t r = a.u + 0x7FFFu + ((a.u >> 16) & 1u);   // RNE
    return (unsigned short)(r >> 16);
}
static __device__ __forceinline__ float bf2f(unsigned short s) {
    union { uint32_t u; float f; } a; a.u = ((uint32_t)s) << 16; return a.f;
}

// ---------------------------------------------------------------------------
// Generic f32 tiled GEMM: C[B,N] = act(concat(A1,A2) @ [Wa;Wb]^T + bias)
// A1:[B,K1], A2:[B,K2], W rows are output features (row-major [N][K]).
// Optionally emits bf16 copy of first NSPLIT columns (for later MFMA use).
// ---------------------------------------------------------------------------
template<int BM, int BN>
__global__ __launch_bounds__(256) void gemm_f32_kernel(
    const float* __restrict__ A1, int K1, const float* __restrict__ A2, int K2,
    const float* __restrict__ Wa, const float* __restrict__ ba,
    const float* __restrict__ Wb, const float* __restrict__ bbias,
    int NSPLIT, int N, int RELU, float* __restrict__ C,
    unsigned short* __restrict__ ghout)
{
    const int K = K1 + K2;
    const int RM = BM / 16, RN = BN / 16;
    __shared__ float As[BM][33];
    __shared__ float Ws[BN][33];
    int t = threadIdx.x;
    int tx = t & 15, ty = t >> 4;
    int bb0 = blockIdx.x * BM;
    int nb0 = blockIdx.y * BN;
    float c[RM][RN];
#pragma unroll
    for (int i = 0; i < RM; ++i)
#pragma unroll
        for (int j = 0; j < RN; ++j) c[i][j] = 0.f;

    for (int k0 = 0; k0 < K; k0 += 32) {
        for (int idx = t; idx < BM * 8; idx += 256) {
            int row = idx >> 3, kq = idx & 7;
            int gk = k0 + kq * 4;
            float4 v;
            if (gk < K1) v = *(const float4*)(A1 + (size_t)(bb0 + row) * K1 + gk);
            else         v = *(const float4*)(A2 + (size_t)(bb0 + row) * K2 + (gk - K1));
            As[row][kq * 4 + 0] = v.x; As[row][kq * 4 + 1] = v.y;
            As[row][kq * 4 + 2] = v.z; As[row][kq * 4 + 3] = v.w;
        }
        for (int idx = t; idx < BN * 8; idx += 256) {
            int row = idx >> 3, kq = idx & 7;
            int gk = k0 + kq * 4;
            int n = nb0 + row;
            const float* wr = (n < NSPLIT) ? (Wa + (size_t)n * K)
                                           : (Wb + (size_t)(n - NSPLIT) * K);
            float4 v = *(const float4*)(wr + gk);
            Ws[row][kq * 4 + 0] = v.x; Ws[row][kq * 4 + 1] = v.y;
            Ws[row][kq * 4 + 2] = v.z; Ws[row][kq * 4 + 3] = v.w;
        }
        __syncthreads();
#pragma unroll
        for (int k = 0; k < 32; ++k) {
            float a[RM], w[RN];
#pragma unroll
            for (int i = 0; i < RM; ++i) a[i] = As[ty * RM + i][k];
#pragma unroll
            for (int j = 0; j < RN; ++j) w[j] = Ws[tx * RN + j][k];
#pragma unroll
            for (int i = 0; i < RM; ++i)
#pragma unroll
                for (int j = 0; j < RN; ++j) c[i][j] = fmaf(a[i], w[j], c[i][j]);
        }
        __syncthreads();
    }
#pragma unroll
    for (int i = 0; i < RM; ++i) {
#pragma unroll
        for (int j = 0; j < RN; ++j) {
            int b = bb0 + ty * RM + i;
            int n = nb0 + tx * RN + j;
            float bias = (n < NSPLIT) ? ba[n] : bbias[n - NSPLIT];
            float v = c[i][j] + bias;
            if (RELU) v = fmaxf(v, 0.f);
            C[(size_t)b * N + n] = v;
            if (ghout != nullptr && n < NSPLIT)
                ghout[(size_t)b * NSPLIT + n] = f2bf(v);
        }
    }
}

// ---------------------------------------------------------------------------
// qprep: per-row inverse norm of query + bf16 copy (plain row-major).
// ---------------------------------------------------------------------------
__global__ __launch_bounds__(256) void qprep_kernel(
    const float* __restrict__ query, float* __restrict__ qinv,
    unsigned short* __restrict__ gq)
{
    int b = blockIdx.x, t = threadIdx.x;
    int lane = t & 63, wid = t >> 6;
    __shared__ float red[4];
    float x0 = query[(size_t)b * 512 + t];
    float x1 = query[(size_t)b * 512 + 256 + t];
    float ss = x0 * x0 + x1 * x1;
#pragma unroll
    for (int off = 32; off; off >>= 1) ss += __shfl_down(ss, off);
    if (lane == 0) red[wid] = ss;
    __syncthreads();
    if (t == 0) qinv[b] = 1.0f / (sqrtf(red[0] + red[1] + red[2] + red[3]) + 1e-8f);
    gq[(size_t)b * 512 + t] = f2bf(x0);
    gq[(size_t)b * 512 + 256 + t] = f2bf(x1);
}

// ---------------------------------------------------------------------------
// sims: approx scores[b][m] = bf16( (q.k) * imp[m]/(|k|+eps) * 1/(|q|+eps) )
// MFMA M-dim = b (256, block-wide), N-dim = keys (128/block). K=512.
// Keys converted f32->bf16 during LDS staging; key norms fused.
// LDS 16B-chunk XOR swizzle => 2-way-max bank aliasing (free).
// ---------------------------------------------------------------------------
__global__ __launch_bounds__(256, 2) void sims_kernel(
    const float* __restrict__ keys, const float* __restrict__ imp,
    const unsigned short* __restrict__ gq, const float* __restrict__ qinv,
    unsigned short* __restrict__ scores)
{
    __shared__ unsigned short Aq[256 * 32];   // 16 KB, [b][32k] swizzled
    __shared__ unsigned short Bk[128 * 32];   // 8 KB,  [m][32k] swizzled
    __shared__ float sumsq_s[128];
    __shared__ float scale_s[128];
    __shared__ float qinv_s[256];
    int t = threadIdx.x, lane = t & 63, wid = t >> 6;
    int fr = lane & 15, fq = lane >> 4;
    int mbase = blockIdx.x * 128;
    int b0 = (wid >> 1) * 128;
    int m0 = (wid & 1) * 64;
    qinv_s[t] = qinv[t];
    if (t < 128) sumsq_s[t] = 0.f;

    f4_t acc[8][4];
#pragma unroll
    for (int i = 0; i < 8; ++i)
#pragma unroll
        for (int j = 0; j < 4; ++j) acc[i][j] = (f4_t){0.f, 0.f, 0.f, 0.f};
    float ps[4] = {0.f, 0.f, 0.f, 0.f};

    const int arow0 = t >> 2, ach = t & 3;
    const int bml0 = t >> 3, bkq = t & 7;

    for (int step = 0; step < 16; ++step) {
        // stage all-256-b q tile (bf16, swizzled)
#pragma unroll
        for (int j = 0; j < 4; ++j) {
            int row = arow0 + 64 * j;
            bf8_t v = *(const bf8_t*)(const void*)(gq + (size_t)row * 512 + step * 32 + ach * 8);
            int slot = ach ^ ((row >> 1) & 3);
            *(bf8_t*)(void*)(&Aq[row * 32 + slot * 8]) = v;
        }
        // stage keys tile: f32 load -> sumsq accum -> bf16 -> LDS
#pragma unroll
        for (int jj = 0; jj < 4; ++jj) {
            int ml = bml0 + 32 * jj;
            int gm = mbase + ml;
            float4 v = {0.f, 0.f, 0.f, 0.f};
            if (gm < MMEM) v = *(const float4*)(keys + (size_t)gm * 512 + step * 32 + bkq * 4);
            ps[jj] += v.x * v.x + v.y * v.y + v.z * v.z + v.w * v.w;
            us4_t pk; pk[0] = f2bf(v.x); pk[1] = f2bf(v.y); pk[2] = f2bf(v.z); pk[3] = f2bf(v.w);
            int slot = (bkq >> 1) ^ ((ml >> 1) & 3);
            *(us4_t*)(void*)(&Bk[ml * 32 + slot * 8 + (bkq & 1) * 4]) = pk;
        }
        __syncthreads();
        bf8_t af[8], bfr[4];
        int slotr = fq ^ ((fr >> 1) & 3);
#pragma unroll
        for (int i = 0; i < 8; ++i)
            af[i] = *(const bf8_t*)(const void*)(&Aq[(b0 + i * 16 + fr) * 32 + slotr * 8]);
#pragma unroll
        for (int j = 0; j < 4; ++j)
            bfr[j] = *(const bf8_t*)(const void*)(&Bk[(m0 + j * 16 + fr) * 32 + slotr * 8]);
#pragma unroll
        for (int i = 0; i < 8; ++i)
#pragma unroll
            for (int j = 0; j < 4; ++j)
                acc[i][j] = __builtin_amdgcn_mfma_f32_16x16x32_bf16(af[i], bfr[j], acc[i][j], 0, 0, 0);
        __syncthreads();
    }
#pragma unroll
    for (int jj = 0; jj < 4; ++jj) atomicAdd(&sumsq_s[bml0 + 32 * jj], ps[jj]);
    __syncthreads();
    if (t < 128) {
        int gm = mbase + t;
        float im = (gm < MMEM) ? imp[gm] : 0.f;
        scale_s[t] = im / (sqrtf(sumsq_s[t]) + 1e-8f);
    }
    __syncthreads();
#pragma unroll
    for (int i = 0; i < 8; ++i) {
        int brow = b0 + i * 16 + fq * 4;
#pragma unroll
        for (int j = 0; j < 4; ++j) {
            int mloc = m0 + j * 16 + fr;
            int gm = mbase + mloc;
            if (gm < MMEM) {
                float sc = scale_s[mloc];
#pragma unroll
                for (int r = 0; r < 4; ++r) {
                    float val = acc[i][j][r] * sc * qinv_s[brow + r];
                    scores[(size_t)(brow + r) * MMEM + gm] = f2bf(val);
                }
            }
        }
    }
}

// ---------------------------------------------------------------------------
// topk+refine: one block per batch row. bf16-score scan -> per-thread top-16
// -> merged global top-16 -> exact f32 rescore -> top-8 -> softmax -> context.
// ---------------------------------------------------------------------------
#define NC 16
__global__ __launch_bounds__(256) void topk_refine_kernel(
    const unsigned short* __restrict__ scores, const float* __restrict__ keys,
    const float* __restrict__ values, const float* __restrict__ imp,
    const float* __restrict__ query, const float* __restrict__ qinv,
    float* __restrict__ context)
{
    int b = blockIdx.x, t = threadIdx.x;
    int lane = t & 63, wid = t >> 6;
    __shared__ float vs[256 * NC];
    __shared__ int   is[256 * NC];
    __shared__ float q_s[512];
    __shared__ float wred[4]; __shared__ int wredi[4];
    __shared__ int   cidx[NC]; __shared__ float csc[NC];
    __shared__ float attn_s[8]; __shared__ int vidx_s[8];

    q_s[t] = query[(size_t)b * 512 + t];
    q_s[t + 256] = query[(size_t)b * 512 + 256 + t];

    int base = t * NC;
#pragma unroll
    for (int p = 0; p < NC; ++p) vs[base + p] = -1e30f;
    float minv = -1e30f; int minp = 0;
    const unsigned short* srow = scores + (size_t)b * MMEM;
    for (int i = 0; i < 391; ++i) {
        int m = t + (i << 8);
        if (m >= MMEM) break;
        float v = bf2f(srow[m]);
        if (v > minv) {
            vs[base + minp] = v; is[base + minp] = m;
            minv = vs[base]; minp = 0;
#pragma unroll
            for (int p = 1; p < NC; ++p) { float q = vs[base + p]; if (q < minv) { minv = q; minp = p; } }
        }
    }
    __syncthreads();
    // extract NC global maxima
    for (int r = 0; r < NC; ++r) {
        float mx = vs[base]; int mp = 0;
#pragma unroll
        for (int p = 1; p < NC; ++p) { float q = vs[base + p]; if (q > mx) { mx = q; mp = p; } }
        int id = base + mp;
#pragma unroll
        for (int off = 32; off; off >>= 1) {
            float ov = __shfl_down(mx, off); int oid = __shfl_down(id, off);
            if (ov > mx) { mx = ov; id = oid; }
        }
        if (lane == 0) { wred[wid] = mx; wredi[wid] = id; }
        __syncthreads();
        if (t == 0) {
            float bmx = wred[0]; int bid = wredi[0];
#pragma unroll
            for (int w = 1; w < 4; ++w) if (wred[w] > bmx) { bmx = wred[w]; bid = wredi[w]; }
            cidx[r] = is[bid];
            vs[bid] = -1e30f;
        }
        __syncthreads();
    }
    // exact f32 rescore: wave wid handles candidates wid*4 .. wid*4+3
    for (int cc = 0; cc < 4; ++cc) {
        int c = wid * 4 + cc;
        int mi = cidx[c];
        const float* krow = keys + (size_t)mi * 512;
        float4 k1 = *(const float4*)(krow + lane * 8);
        float4 k2 = *(const float4*)(krow + lane * 8 + 4);
        int q0 = lane * 8;
        float dot = k1.x * q_s[q0] + k1.y * q_s[q0 + 1] + k1.z * q_s[q0 + 2] + k1.w * q_s[q0 + 3]
                  + k2.x * q_s[q0 + 4] + k2.y * q_s[q0 + 5] + k2.z * q_s[q0 + 6] + k2.w * q_s[q0 + 7];
        float nr = k1.x * k1.x + k1.y * k1.y + k1.z * k1.z + k1.w * k1.w
                 + k2.x * k2.x + k2.y * k2.y + k2.z * k2.z + k2.w * k2.w;
#pragma unroll
        for (int off = 32; off; off >>= 1) {
            dot += __shfl_down(dot, off);
            nr  += __shfl_down(nr, off);
        }
        if (lane == 0)
            csc[c] = dot * qinv[b] * imp[mi] / (sqrtf(nr) + 1e-8f);
    }
    __syncthreads();
    if (t == 0) {
        unsigned used = 0;
        float sv[8]; int si[8];
#pragma unroll
        for (int r = 0; r < 8; ++r) {
            float bm = -1e31f; int bp = 0;
            for (int p = 0; p < NC; ++p)
                if (!((used >> p) & 1u) && csc[p] > bm) { bm = csc[p]; bp = p; }
            used |= 1u << bp; sv[r] = bm; si[r] = cidx[bp];
        }
        float mx = sv[0];
        float ee[8]; float den = 0.f;
#pragma unroll
        for (int r = 0; r < 8; ++r) { ee[r] = expf(sv[r] - mx); den += ee[r]; }
#pragma unroll
        for (int r = 0; r < 8; ++r) { attn_s[r] = ee[r] / den; vidx_s[r] = si[r]; }
    }
    __syncthreads();
    int d0 = t * 2;
    float c0 = 0.f, c1 = 0.f;
#pragma unroll
    for (int r = 0; r < 8; ++r) {
        float w = attn_s[r];
        const float* vrow = values + (size_t)vidx_s[r] * 512;
        float2 vv = *(const float2*)(vrow + d0);
        c0 += w * vv.x; c1 += w * vv.y;
    }
    float2 outv; outv.x = c0; outv.y = c1;
    *(float2*)(context + (size_t)b * 512 + d0) = outv;
}

// ---------------------------------------------------------------------------
// logits: out[b][v] = (h_p @ Wp2^T)[b][v] + bp2[v].  Same MFMA structure as
// sims (M-dim = b block-wide, N-dim = vocab rows, K=1024).
// ---------------------------------------------------------------------------
__global__ __launch_bounds__(256, 2) void logits_kernel(
    const float* __restrict__ Wp2, const float* __restrict__ bp2,
    const unsigned short* __restrict__ gh, float* __restrict__ out)
{
    __shared__ unsigned short Ah[256 * 32];
    __shared__ unsigned short Bw[128 * 32];
    __shared__ float bias_s[128];
    int t = threadIdx.x, lane = t & 63, wid = t >> 6;
    int fr = lane & 15, fq = lane >> 4;
    int vbase = blockIdx.x * 128;
    int b0 = (wid >> 1) * 128;
    int m0 = (wid & 1) * 64;
    if (t < 128) { int gv = vbase + t; bias_s[t] = (gv < VDIM) ? bp2[gv] : 0.f; }

    f4_t acc[8][4];
#pragma unroll
    for (int i = 0; i < 8; ++i)
#pragma unroll
        for (int j = 0; j < 4; ++j) acc[i][j] = (f4_t){0.f, 0.f, 0.f, 0.f};

    const int arow0 = t >> 2, ach = t & 3;
    const int bml0 = t >> 3, bkq = t & 7;

    for (int step = 0; step < 32; ++step) {
#pragma unroll
        for (int j = 0; j < 4; ++j) {
            int row = arow0 + 64 * j;
            bf8_t v = *(const bf8_t*)(const void*)(gh + (size_t)row * 1024 + step * 32 + ach * 8);
            int slot = ach ^ ((row >> 1) & 3);
            *(bf8_t*)(void*)(&Ah[row * 32 + slot * 8]) = v;
        }
#pragma unroll
        for (int jj = 0; jj < 4; ++jj) {
            int ml = bml0 + 32 * jj;
            int gv = vbase + ml;
            float4 v = {0.f, 0.f, 0.f, 0.f};
            if (gv < VDIM) v = *(const float4*)(Wp2 + (size_t)gv * 1024 + step * 32 + bkq * 4);
            us4_t pk; pk[0] = f2bf(v.x); pk[1] = f2bf(v.y); pk[2] = f2bf(v.z); pk[3] = f2bf(v.w);
            int slot = (bkq >> 1) ^ ((ml >> 1) & 3);
            *(us4_t*)(void*)(&Bw[ml * 32 + slot * 8 + (bkq & 1) * 4]) = pk;
        }
        __syncthreads();
        bf8_t af[8], bfr[4];
        int slotr = fq ^ ((fr >> 1) & 3);
#pragma unroll
        for (int i = 0; i < 8; ++i)
            af[i] = *(const bf8_t*)(const void*)(&Ah[(b0 + i * 16 + fr) * 32 + slotr * 8]);
#pragma unroll
        for (int j = 0; j < 4; ++j)
            bfr[j] = *(const bf8_t*)(const void*)(&Bw[(m0 + j * 16 + fr) * 32 + slotr * 8]);
#pragma unroll
        for (int i = 0; i < 8; ++i)
#pragma unroll
            for (int j = 0; j < 4; ++j)
                acc[i][j] = __builtin_amdgcn_mfma_f32_16x16x32_bf16(af[i], bfr[j], acc[i][j], 0, 0, 0);
        __syncthreads();
    }
#pragma unroll
    for (int i = 0; i < 8; ++i) {
        int brow = b0 + i * 16 + fq * 4;
#pragma unroll
        for (int j = 0; j < 4; ++j) {
            int vloc = m0 + j * 16 + fr;
            int gv = vbase + vloc;
            if (gv < VDIM) {
                float bias = bias_s[vloc];
#pragma unroll
                for (int r = 0; r < 4; ++r)
                    out[(size_t)(brow + r) * VDIM + gv] = acc[i][j][r] + bias;
            }
        }
    }
}

// ---------------------------------------------------------------------------
// value head: out[B*V + b] = h_v[b,:] . Wv2 + bv2.  One wave per batch row.
// ---------------------------------------------------------------------------
__global__ __launch_bounds__(256) void value_kernel(
    const float* __restrict__ hcomb, const float* __restrict__ Wv2,
    const float* __restrict__ bv2, float* __restrict__ out)
{
    int lane = threadIdx.x & 63, wid = threadIdx.x >> 6;
    int b = blockIdx.x * 4 + wid;
    float s = 0.f;
#pragma unroll
    for (int i = 0; i < 16; ++i) {
        int k = lane + 64 * i;
        s += hcomb[(size_t)b * 2048 + 1024 + k] * Wv2[k];
    }
#pragma unroll
    for (int off = 32; off; off >>= 1) s += __shfl_down(s, off);
    if (lane == 0) out[(size_t)BB * VDIM + b] = s + bv2[0];
}

// ---------------------------------------------------------------------------
extern "C" void kernel_launch(void* const* d_in, const int* in_sizes, int n_in,
                              void* d_out, int out_size, void* d_ws, size_t ws_size,
                              hipStream_t stream)
{
    const float* hidden = (const float*)d_in[0];
    const float* keys   = (const float*)d_in[1];
    const float* values = (const float*)d_in[2];
    const float* imp    = (const float*)d_in[3];
    const float* Wq  = (const float*)d_in[4];
    const float* bq  = (const float*)d_in[5];
    const float* Wp1 = (const float*)d_in[6];
    const float* bp1 = (const float*)d_in[7];
    const float* Wp2 = (const float*)d_in[8];
    const float* bp2 = (const float*)d_in[9];
    const float* Wv1 = (const float*)d_in[10];
    const float* bv1 = (const float*)d_in[11];
    const float* Wv2 = (const float*)d_in[12];
    const float* bv2 = (const float*)d_in[13];
    // d_in[14] = top_k (always 8 in this problem's setup)
    float* out = (float*)d_out;
    char* ws = (char*)d_ws;

    float*          query   = (float*)(ws + 0);                      // 524288 B
    float*          qinv    = (float*)(ws + 524288);                 //   1024 B
    unsigned short* gq      = (unsigned short*)(ws + 525312);        // 262144 B
    float*          context = (float*)(ws + 787456);                 // 524288 B
    float*          hcomb   = (float*)(ws + 1311744);                // 2097152 B
    unsigned short* gh      = (unsigned short*)(ws + 3408896);       // 524288 B
    unsigned short* scores  = (unsigned short*)(ws + 3933184);       // 51200000 B
    // total ws usage: ~55.2 MB

    // 1. query = hidden @ Wq^T + bq   (exact f32 — selection depends on it)
    gemm_f32_kernel<16, 64><<<dim3(16, 8), 256, 0, stream>>>(
        hidden, 1024, nullptr, 0, Wq, bq, nullptr, nullptr, 512, 512, 0, query, nullptr);
    // 2. query norms + bf16 copy
    qprep_kernel<<<256, 256, 0, stream>>>(query, qinv, gq);
    // 3. approx sims (bf16 MFMA) -> bf16 score matrix
    sims_kernel<<<782, 256, 0, stream>>>(keys, imp, gq, qinv, scores);
    // 4. per-row top-16 candidates -> exact rescore -> top-8 softmax -> context
    topk_refine_kernel<<<256, 256, 0, stream>>>(scores, keys, values, imp, query, qinv, context);
    // 5. h_p / h_v = relu([hidden|context] @ [Wp1;Wv1]^T + b)  (f32, emits bf16 h_p)
    gemm_f32_kernel<32, 64><<<dim3(8, 32), 256, 0, stream>>>(
        hidden, 1024, context, 512, Wp1, bp1, Wv1, bv1, 1024, 2048, 1, hcomb, gh);
    // 6. logits = h_p @ Wp2^T + bp2  (bf16 MFMA, f32 out)
    logits_kernel<<<393, 256, 0, stream>>>(Wp2, bp2, gh, out);
    // 7. value head
    value_kernel<<<64, 256, 0, stream>>>(hcomb, Wv2, bv2, out);
}